// Round 3
// baseline (910.620 us; speedup 1.0000x reference)
//
#include <hip/hip_runtime.h>
#include <stdint.h>

constexpr int N_NODES = 50000;
constexpr int N_EDGES = 800000;
constexpr int HD      = 128;
constexpr int NREL    = 8;
constexpr int NBUCK   = N_NODES * NREL;   // 400000 (dst,etype) buckets

typedef unsigned short ushortT;
using bf16x8 = __attribute__((ext_vector_type(8))) short;
using f32x4  = __attribute__((ext_vector_type(4))) float;

__device__ __forceinline__ float b2f(uint32_t lo16){
  uint32_t x = lo16 << 16; float f; __builtin_memcpy(&f,&x,4); return f;
}
__device__ __forceinline__ uint16_t f2b(float f){
  uint32_t x; __builtin_memcpy(&x,&f,4);
  uint32_t r = (x + 0x7FFFu + ((x>>16)&1u)) >> 16;
  return (uint16_t)r;
}

// ---------------- utility ----------------
__global__ void k_zero2(int* __restrict__ a, int* __restrict__ b, int n){
  int i = blockIdx.x*blockDim.x + threadIdx.x;
  if(i<n){ a[i]=0; b[i]=0; }
}

// ---------------- CSR build over (dst*8+etype) buckets ----------------
__global__ void k_hist(const int* __restrict__ dst, const int* __restrict__ et,
                       int* __restrict__ deg){
  int i = blockIdx.x*blockDim.x + threadIdx.x;
  if(i<N_EDGES) atomicAdd(&deg[dst[i]*NREL + et[i]],1);
}

__global__ void k_scan1(const int* __restrict__ in, int* __restrict__ out,
                        int* __restrict__ part, int n){
  __shared__ int sm[256];
  int t = threadIdx.x; int i = blockIdx.x*256+t;
  int v = (i<n)? in[i] : 0;
  sm[t]=v; __syncthreads();
  for(int off=1; off<256; off<<=1){
    int x = (t>=off)? sm[t-off] : 0;
    __syncthreads();
    sm[t]+=x;
    __syncthreads();
  }
  if(i<n) out[i]=sm[t]-v;       // exclusive within block
  if(t==255) part[blockIdx.x]=sm[255];
}

__global__ void k_scan2(int* __restrict__ part, int nb){
  __shared__ int sm[256];
  int t=threadIdx.x;
  int v=(t<nb)? part[t] : 0;
  sm[t]=v; __syncthreads();
  for(int off=1; off<256; off<<=1){
    int x=(t>=off)? sm[t-off]:0;
    __syncthreads();
    sm[t]+=x;
    __syncthreads();
  }
  if(t<nb) part[t]=sm[t]-v;
}

__global__ void k_scan3(int* __restrict__ out, const int* __restrict__ part, int n){
  int i = blockIdx.x*blockDim.x+threadIdx.x;
  if(i<n) out[i]+=part[blockIdx.x];
}

__global__ void k_scatter(const int* __restrict__ src, const int* __restrict__ et,
                          const float* __restrict__ w, const int* __restrict__ dst,
                          const int* __restrict__ offs, int* __restrict__ cur,
                          int* __restrict__ src_s, float* __restrict__ w_s){
  int i = blockIdx.x*blockDim.x + threadIdx.x;
  if(i<N_EDGES){
    int b = dst[i]*NREL + et[i];
    int pos = offs[b] + atomicAdd(&cur[b],1);
    src_s[pos]=src[i]; w_s[pos]=w[i];
  }
}

// ---------------- f32 -> bf16 table convert ----------------
__global__ void k_f2b(const float* __restrict__ in, ushortT* __restrict__ out, int n4){
  int i = blockIdx.x*blockDim.x + threadIdx.x;
  if(i<n4){
    float4 v = ((const float4*)in)[i];
    ushort4 o;
    o.x=f2b(v.x); o.y=f2b(v.y); o.z=f2b(v.z); o.w=f2b(v.w);
    ((ushort4*)out)[i]=o;
  }
}

// ---------------- Wt[o][r*128+k] = sum_b comp[r,b] V[b,k,o] (both layers) ----
__global__ void k_relw(const float* __restrict__ comp1, const float* __restrict__ V1,
                       const float* __restrict__ comp2, const float* __restrict__ V2,
                       ushortT* __restrict__ Wt1, ushortT* __restrict__ Wt2){
  int t = blockIdx.x*blockDim.x + threadIdx.x;
  int layer = t >> 17;             // 0 or 1 (2*131072 threads)
  t &= 131071;
  const float* comp = layer? comp2 : comp1;
  const float* V    = layer? V2    : V1;
  ushortT* Wt       = layer? Wt2   : Wt1;
  int o  = t >> 10;                // 0..127
  int rk = t & 1023;
  int r  = rk >> 7, k = rk & 127;
  float s=0.f;
  #pragma unroll
  for(int b=0;b<NREL;b++) s += comp[r*NREL+b]*V[(b<<14) + k*HD + o];
  Wt[t]=f2b(s);
}

// ---------------- fused aggregate + GEMM ----------------
// out[n] = sum_r (sum_{e in bucket(n,r)} w_e * x[src_e]) @ W_r  (+bias, relu)
constexpr int BM=64, LDK=136;   // 272B row: bank shift 4/row -> ~2-way (free)
__global__ void __launch_bounds__(256)
k_fused(const ushortT* __restrict__ xb,   // [N][128] bf16 gather table
        const ushortT* __restrict__ Wt,   // [128][1024] bf16 (o-major)
        const int* __restrict__ offs, const int* __restrict__ deg,
        const int* __restrict__ src_s, const float* __restrict__ w_s,
        const float* __restrict__ bias,
        float* __restrict__ outF,         // layer2: f32 out (or null)
        ushortT* __restrict__ outB,       // layer1: bf16 out (or null)
        int relu){
  __shared__ ushortT Asm[BM][LDK];
  __shared__ ushortT Bsm[128][LDK];
  int tid = threadIdx.x;
  int wid = tid>>6, lane = tid&63;
  int l15 = lane&15, lhi = lane>>4;
  int row0 = blockIdx.x*BM;
  int wr = (wid>>1)*32, wc = (wid&1)*64;   // wave tile 32x64
  f32x4 acc[2][4] = {};
  for(int r=0;r<NREL;r++){
    // stage B_r: 128 rows x 128 shorts, 2048 16B-chunks, 8 rounds of 256
    #pragma unroll
    for(int q=0;q<8;q++){
      int slot = q*256 + tid;
      int c = slot>>4, kb8 = (slot&15)*8;
      *(bf16x8*)&Bsm[c][kb8] = *(const bf16x8*)&Wt[(size_t)c*1024 + r*HD + kb8];
    }
    // aggregate: wave wid handles nodes row0+wid*16 .. +15
    for(int i=0;i<16;i++){
      int rloc = wid*16 + i;
      int node = row0 + rloc;
      float a0=0.f, a1=0.f;
      if(node < N_NODES){
        int b = node*NREL + r;
        int beg = offs[b], cnt = deg[b];
        for(int j=0;j<cnt;j++){
          int s   = src_s[beg+j];
          float w = w_s[beg+j];
          uint32_t u = *(const uint32_t*)&xb[(size_t)s*HD + lane*2];
          a0 += w * b2f(u & 0xFFFFu);
          a1 += w * b2f(u >> 16);
        }
      }
      uint32_t pk = (uint32_t)f2b(a0) | ((uint32_t)f2b(a1)<<16);
      *(uint32_t*)&Asm[rloc][lane*2] = pk;
    }
    __syncthreads();
    #pragma unroll
    for(int kk=0;kk<4;kk++){
      bf16x8 af[2], bfr[4];
      #pragma unroll
      for(int m=0;m<2;m++)  af[m]  = *(const bf16x8*)&Asm[wr + m*16 + l15][kk*32 + lhi*8];
      #pragma unroll
      for(int n=0;n<4;n++)  bfr[n] = *(const bf16x8*)&Bsm[wc + n*16 + l15][kk*32 + lhi*8];
      #pragma unroll
      for(int m=0;m<2;m++)
        #pragma unroll
        for(int n=0;n<4;n++)
          acc[m][n] = __builtin_amdgcn_mfma_f32_16x16x32_bf16(af[m], bfr[n], acc[m][n], 0,0,0);
    }
    __syncthreads();   // protect tiles before next relation overwrites
  }
  // epilogue: D row=lhi*4+j, col=l15 per 16x16 fragment
  #pragma unroll
  for(int m=0;m<2;m++){
    #pragma unroll
    for(int j=0;j<4;j++){
      int grow = row0 + wr + m*16 + lhi*4 + j;
      if(grow < N_NODES){
        #pragma unroll
        for(int n=0;n<4;n++){
          int col = wc + n*16 + l15;
          float v = acc[m][n][j] + bias[col];
          if(relu) v = fmaxf(v, 0.f);
          if(outF) outF[(size_t)grow*HD + col] = v;
          else     outB[(size_t)grow*HD + col] = f2b(v);
        }
      }
    }
  }
}

extern "C" void kernel_launch(void* const* d_in, const int* in_sizes, int n_in,
                              void* d_out, int out_size, void* d_ws, size_t ws_size,
                              hipStream_t stream){
  const float* feat  = (const float*)d_in[0];
  const int*   etyp  = (const int*)  d_in[1];
  const float* ew    = (const float*)d_in[2];
  const int*   src   = (const int*)  d_in[3];
  const int*   dst   = (const int*)  d_in[4];
  const float* comp1 = (const float*)d_in[5];
  const float* V1    = (const float*)d_in[6];
  const float* bias1 = (const float*)d_in[7];
  const float* comp2 = (const float*)d_in[8];
  const float* V2    = (const float*)d_in[9];
  const float* bias2 = (const float*)d_in[10];
  float* out = (float*)d_out;

  char* p = (char*)d_ws;
  auto alloc = [&](size_t bytes)->char* {
    char* q = p; p += (bytes + 255) & ~(size_t)255; return q;
  };
  ushortT* Wt1   = (ushortT*)alloc((size_t)HD*NREL*HD*2);      // 256 KB
  ushortT* Wt2   = (ushortT*)alloc((size_t)HD*NREL*HD*2);      // 256 KB
  ushortT* xb    = (ushortT*)alloc((size_t)N_NODES*HD*2);      // 12.8 MB
  ushortT* hmid  = (ushortT*)alloc((size_t)N_NODES*HD*2);      // 12.8 MB
  int*   deg   = (int*)  alloc((size_t)NBUCK*4);
  int*   offs  = (int*)  alloc((size_t)NBUCK*4);
  int*   cur   = (int*)  alloc((size_t)NBUCK*4);
  int*   part1 = (int*)  alloc(2048*4);
  int*   part2 = (int*)  alloc(256*4);
  int*   src_s = (int*)  alloc((size_t)N_EDGES*4);
  float* w_s   = (float*)alloc((size_t)N_EDGES*4);

  // ---- CSR build over 400k (dst,etype) buckets ----
  int zb = (NBUCK+255)/256;           // 1563
  k_zero2<<<zb,256,0,stream>>>(deg,cur,NBUCK);
  k_hist<<<(N_EDGES+255)/256,256,0,stream>>>(dst,etyp,deg);
  int nb1 = (NBUCK+255)/256;          // 1563
  int nb2 = (nb1+255)/256;            // 7
  k_scan1<<<nb1,256,0,stream>>>(deg,offs,part1,NBUCK);
  k_scan1<<<nb2,256,0,stream>>>(part1,part1,part2,nb1);
  k_scan2<<<1,256,0,stream>>>(part2,nb2);
  k_scan3<<<nb2,256,0,stream>>>(part1,part2,nb1);
  k_scan3<<<nb1,256,0,stream>>>(offs,part1,NBUCK);
  k_scatter<<<(N_EDGES+255)/256,256,0,stream>>>(src,etyp,ew,dst,offs,cur,src_s,w_s);

  // ---- feature table to bf16; relation weights for both layers ----
  int n4 = N_NODES*HD/4;
  k_f2b<<<(n4+255)/256,256,0,stream>>>(feat, xb, n4);
  k_relw<<<(2*HD*NREL*HD+255)/256,256,0,stream>>>(comp1,V1,comp2,V2,Wt1,Wt2);

  int grid = (N_NODES + BM - 1)/BM;   // 782
  // ---- layer 1 (fused agg+gemm, bf16 out, relu) ----
  k_fused<<<grid,256,0,stream>>>(xb,   Wt1, offs, deg, src_s, w_s, bias1, nullptr, hmid, 1);
  // ---- layer 2 (fused agg+gemm, f32 out) ----
  k_fused<<<grid,256,0,stream>>>(hmid, Wt2, offs, deg, src_s, w_s, bias2, out, nullptr, 0);
}

// Round 4
// 360.680 us; speedup vs baseline: 2.5247x; 2.5247x over previous
//
#include <hip/hip_runtime.h>
#include <stdint.h>

constexpr int N_NODES = 50000;
constexpr int N_EDGES = 800000;
constexpr int HD      = 128;
constexpr int NREL    = 8;
constexpr int NBUCK   = N_NODES * NREL;   // 400000 (dst,etype) buckets

typedef unsigned short ushortT;
using bf16x8 = __attribute__((ext_vector_type(8))) short;
using f32x4  = __attribute__((ext_vector_type(4))) float;

__device__ __forceinline__ float b2f(uint32_t lo16){
  uint32_t x = lo16 << 16; float f; __builtin_memcpy(&f,&x,4); return f;
}
__device__ __forceinline__ uint16_t f2b(float f){
  uint32_t x; __builtin_memcpy(&x,&f,4);
  uint32_t r = (x + 0x7FFFu + ((x>>16)&1u)) >> 16;
  return (uint16_t)r;
}

// ---------------- utility ----------------
__global__ void k_zero2(int* __restrict__ a, int* __restrict__ b, int n){
  int i = blockIdx.x*blockDim.x + threadIdx.x;
  if(i<n){ a[i]=0; b[i]=0; }
}

// ---------------- CSR build over (dst*8+etype) buckets ----------------
__global__ void k_hist(const int* __restrict__ dst, const int* __restrict__ et,
                       int* __restrict__ deg){
  int i = blockIdx.x*blockDim.x + threadIdx.x;
  if(i<N_EDGES) atomicAdd(&deg[dst[i]*NREL + et[i]],1);
}

__global__ void k_scan1(const int* __restrict__ in, int* __restrict__ out,
                        int* __restrict__ part, int n){
  __shared__ int sm[256];
  int t = threadIdx.x; int i = blockIdx.x*256+t;
  int v = (i<n)? in[i] : 0;
  sm[t]=v; __syncthreads();
  for(int off=1; off<256; off<<=1){
    int x = (t>=off)? sm[t-off] : 0;
    __syncthreads();
    sm[t]+=x;
    __syncthreads();
  }
  if(i<n) out[i]=sm[t]-v;       // exclusive within block
  if(t==255) part[blockIdx.x]=sm[255];
}

__global__ void k_scan2(int* __restrict__ part, int nb){
  __shared__ int sm[256];
  int t=threadIdx.x;
  int v=(t<nb)? part[t] : 0;
  sm[t]=v; __syncthreads();
  for(int off=1; off<256; off<<=1){
    int x=(t>=off)? sm[t-off]:0;
    __syncthreads();
    sm[t]+=x;
    __syncthreads();
  }
  if(t<nb) part[t]=sm[t]-v;
}

__global__ void k_scan3(int* __restrict__ out, const int* __restrict__ part, int n){
  int i = blockIdx.x*blockDim.x+threadIdx.x;
  if(i<n) out[i]+=part[blockIdx.x];
}

__global__ void k_scatter(const int* __restrict__ src, const int* __restrict__ et,
                          const float* __restrict__ w, const int* __restrict__ dst,
                          const int* __restrict__ offs, int* __restrict__ cur,
                          int2* __restrict__ es){
  int i = blockIdx.x*blockDim.x + threadIdx.x;
  if(i<N_EDGES){
    int b = dst[i]*NREL + et[i];
    int pos = offs[b] + atomicAdd(&cur[b],1);
    int2 e; e.x = src[i]; e.y = __float_as_int(w[i]);
    es[pos] = e;
  }
}

// ---------------- f32 -> bf16 table convert ----------------
__global__ void k_f2b(const float* __restrict__ in, ushortT* __restrict__ out, int n4){
  int i = blockIdx.x*blockDim.x + threadIdx.x;
  if(i<n4){
    float4 v = ((const float4*)in)[i];
    ushort4 o;
    o.x=f2b(v.x); o.y=f2b(v.y); o.z=f2b(v.z); o.w=f2b(v.w);
    ((ushort4*)out)[i]=o;
  }
}

// ---------------- Wt[o][r*128+k] = sum_b comp[r,b] V[b,k,o] (both layers) ----
__global__ void k_relw(const float* __restrict__ comp1, const float* __restrict__ V1,
                       const float* __restrict__ comp2, const float* __restrict__ V2,
                       ushortT* __restrict__ Wt1, ushortT* __restrict__ Wt2){
  int t = blockIdx.x*blockDim.x + threadIdx.x;
  int layer = t >> 17;             // 0 or 1 (2*131072 threads)
  t &= 131071;
  const float* comp = layer? comp2 : comp1;
  const float* V    = layer? V2    : V1;
  ushortT* Wt       = layer? Wt2   : Wt1;
  int o  = t >> 10;                // 0..127
  int rk = t & 1023;
  int r  = rk >> 7, k = rk & 127;
  float s=0.f;
  #pragma unroll
  for(int b=0;b<NREL;b++) s += comp[r*NREL+b]*V[(b<<14) + k*HD + o];
  Wt[t]=f2b(s);
}

// ---------------- aggregate-first: one WAVE per (dst,rel) bucket ----------------
// Acat[b][128] bf16, b = node*8+r  (== A[node][1024] r-major)
__global__ void __launch_bounds__(256)
k_agg(const ushortT* __restrict__ xb,   // [N][128] bf16 gather table
      const int* __restrict__ offs, const int* __restrict__ deg,
      const int2* __restrict__ es,      // packed (src, w)
      ushortT* __restrict__ Acat){
  int b = blockIdx.x*4 + (threadIdx.x>>6);
  int lane = threadIdx.x & 63;
  if(b >= NBUCK) return;
  int beg = offs[b], cnt = deg[b];
  const int2* ep = es + beg;
  float a0=0.f, a1=0.f;
  int j=0;
  for(; j+2<=cnt; j+=2){
    int2 e0 = ep[j], e1 = ep[j+1];
    uint32_t u0 = *(const uint32_t*)&xb[(size_t)e0.x*HD + lane*2];
    uint32_t u1 = *(const uint32_t*)&xb[(size_t)e1.x*HD + lane*2];
    float w0 = __int_as_float(e0.y), w1 = __int_as_float(e1.y);
    a0 += w0 * b2f(u0 & 0xFFFFu);
    a1 += w0 * b2f(u0 >> 16);
    a0 += w1 * b2f(u1 & 0xFFFFu);
    a1 += w1 * b2f(u1 >> 16);
  }
  if(j < cnt){
    int2 e0 = ep[j];
    uint32_t u0 = *(const uint32_t*)&xb[(size_t)e0.x*HD + lane*2];
    float w0 = __int_as_float(e0.y);
    a0 += w0 * b2f(u0 & 0xFFFFu);
    a1 += w0 * b2f(u0 >> 16);
  }
  uint32_t pk = (uint32_t)f2b(a0) | ((uint32_t)f2b(a1)<<16);
  *(uint32_t*)&Acat[(size_t)b*HD + lane*2] = pk;
}

// ---------------- MFMA GEMM: out[M][128] = Acat[M][1024] @ Wt^T ----------------
constexpr int BM=64, BN=128, BK=64, LDK=72;   // pad: 144B row, 2-way bank alias (free)
__global__ void __launch_bounds__(256)
k_gemm(const ushortT* __restrict__ A,   // [M][1024] bf16
       const ushortT* __restrict__ Wt,  // [128][1024] bf16 (B transposed)
       const float* __restrict__ bias,
       float* __restrict__ outF,        // layer2 output (f32) or null
       ushortT* __restrict__ outB,      // layer1 output (bf16) or null
       int M, int relu){
  __shared__ ushortT Asm[BM][LDK];
  __shared__ ushortT Bsm[BN][LDK];
  int tid = threadIdx.x;
  int wid = tid>>6, lane = tid&63;
  int l15 = lane&15, lhi = lane>>4;
  int row0 = blockIdx.x*BM;
  int wr = (wid>>1)*32, wc = (wid&1)*64;   // wave tile 32x64
  f32x4 acc[2][4] = {};
  for(int kt=0; kt<NREL*HD; kt+=BK){
    #pragma unroll
    for(int q=0;q<2;q++){
      int slot = q*256 + tid;
      int r = slot>>3, kb8 = (slot&7)*8;
      int grow = row0 + r; if(grow >= M) grow = M-1;
      *(bf16x8*)&Asm[r][kb8] = *(const bf16x8*)&A[(size_t)grow*1024 + kt + kb8];
    }
    #pragma unroll
    for(int q=0;q<4;q++){
      int slot = q*256 + tid;
      int c = slot>>3, kb8 = (slot&7)*8;
      *(bf16x8*)&Bsm[c][kb8] = *(const bf16x8*)&Wt[(size_t)c*1024 + kt + kb8];
    }
    __syncthreads();
    #pragma unroll
    for(int kk=0;kk<2;kk++){
      bf16x8 af[2], bfr[4];
      #pragma unroll
      for(int m=0;m<2;m++)  af[m]  = *(const bf16x8*)&Asm[wr + m*16 + l15][kk*32 + lhi*8];
      #pragma unroll
      for(int n=0;n<4;n++)  bfr[n] = *(const bf16x8*)&Bsm[wc + n*16 + l15][kk*32 + lhi*8];
      #pragma unroll
      for(int m=0;m<2;m++)
        #pragma unroll
        for(int n=0;n<4;n++)
          acc[m][n] = __builtin_amdgcn_mfma_f32_16x16x32_bf16(af[m], bfr[n], acc[m][n], 0,0,0);
    }
    __syncthreads();
  }
  #pragma unroll
  for(int m=0;m<2;m++){
    #pragma unroll
    for(int j=0;j<4;j++){
      int grow = row0 + wr + m*16 + lhi*4 + j;
      if(grow < M){
        #pragma unroll
        for(int n=0;n<4;n++){
          int col = wc + n*16 + l15;
          float v = acc[m][n][j] + bias[col];
          if(relu) v = fmaxf(v, 0.f);
          if(outF) outF[(size_t)grow*HD + col] = v;
          else     outB[(size_t)grow*HD + col] = f2b(v);
        }
      }
    }
  }
}

extern "C" void kernel_launch(void* const* d_in, const int* in_sizes, int n_in,
                              void* d_out, int out_size, void* d_ws, size_t ws_size,
                              hipStream_t stream){
  const float* feat  = (const float*)d_in[0];
  const int*   etyp  = (const int*)  d_in[1];
  const float* ew    = (const float*)d_in[2];
  const int*   src   = (const int*)  d_in[3];
  const int*   dst   = (const int*)  d_in[4];
  const float* comp1 = (const float*)d_in[5];
  const float* V1    = (const float*)d_in[6];
  const float* bias1 = (const float*)d_in[7];
  const float* comp2 = (const float*)d_in[8];
  const float* V2    = (const float*)d_in[9];
  const float* bias2 = (const float*)d_in[10];
  float* out = (float*)d_out;

  char* p = (char*)d_ws;
  auto alloc = [&](size_t bytes)->char* {
    char* q = p; p += (bytes + 255) & ~(size_t)255; return q;
  };
  ushortT* Wt1   = (ushortT*)alloc((size_t)HD*NREL*HD*2);        // 256 KB
  ushortT* Wt2   = (ushortT*)alloc((size_t)HD*NREL*HD*2);        // 256 KB
  ushortT* Acat  = (ushortT*)alloc((size_t)N_NODES*NREL*HD*2);   // 102.4 MB
  ushortT* xb    = (ushortT*)alloc((size_t)N_NODES*HD*2);        // 12.8 MB
  ushortT* hmid  = (ushortT*)alloc((size_t)N_NODES*HD*2);        // 12.8 MB
  int*   deg   = (int*)  alloc((size_t)NBUCK*4);
  int*   offs  = (int*)  alloc((size_t)NBUCK*4);
  int*   cur   = (int*)  alloc((size_t)NBUCK*4);
  int*   part1 = (int*)  alloc(2048*4);
  int*   part2 = (int*)  alloc(256*4);
  int2*  es    = (int2*) alloc((size_t)N_EDGES*8);

  // ---- CSR build over 400k (dst,etype) buckets ----
  int zb = (NBUCK+255)/256;           // 1563
  k_zero2<<<zb,256,0,stream>>>(deg,cur,NBUCK);
  k_hist<<<(N_EDGES+255)/256,256,0,stream>>>(dst,etyp,deg);
  int nb1 = (NBUCK+255)/256;          // 1563
  int nb2 = (nb1+255)/256;            // 7
  k_scan1<<<nb1,256,0,stream>>>(deg,offs,part1,NBUCK);
  k_scan1<<<nb2,256,0,stream>>>(part1,part1,part2,nb1);
  k_scan2<<<1,256,0,stream>>>(part2,nb2);
  k_scan3<<<nb2,256,0,stream>>>(part1,part2,nb1);
  k_scan3<<<nb1,256,0,stream>>>(offs,part1,NBUCK);
  k_scatter<<<(N_EDGES+255)/256,256,0,stream>>>(src,etyp,ew,dst,offs,cur,es);

  // ---- feature table to bf16; relation weights for both layers ----
  int n4 = N_NODES*HD/4;
  k_f2b<<<(n4+255)/256,256,0,stream>>>(feat, xb, n4);
  k_relw<<<(2*HD*NREL*HD+255)/256,256,0,stream>>>(comp1,V1,comp2,V2,Wt1,Wt2);

  int aggGrid  = (NBUCK + 3)/4;           // 100000 blocks, 4 waves each
  int gemmGrid = (N_NODES + BM - 1)/BM;   // 782
  // ---- layer 1 ----
  k_agg<<<aggGrid,256,0,stream>>>(xb,   offs, deg, es, Acat);
  k_gemm<<<gemmGrid,256,0,stream>>>(Acat, Wt1, bias1, nullptr, hmid, N_NODES, 1);
  // ---- layer 2 ----
  k_agg<<<aggGrid,256,0,stream>>>(hmid, offs, deg, es, Acat);
  k_gemm<<<gemmGrid,256,0,stream>>>(Acat, Wt2, bias2, out, nullptr, N_NODES, 0);
}

// Round 5
// 270.181 us; speedup vs baseline: 3.3704x; 1.3350x over previous
//
#include <hip/hip_runtime.h>
#include <stdint.h>

constexpr int N_NODES = 50000;
constexpr int N_EDGES = 800000;
constexpr int HD      = 128;
constexpr int NREL    = 8;
constexpr int NBUCK   = N_NODES * NREL;   // 400000 (dst,etype) buckets

typedef unsigned short ushortT;
using bf16x8 = __attribute__((ext_vector_type(8))) short;
using f32x4  = __attribute__((ext_vector_type(4))) float;

__device__ __forceinline__ float b2f(uint32_t lo16){
  uint32_t x = lo16 << 16; float f; __builtin_memcpy(&f,&x,4); return f;
}
__device__ __forceinline__ uint16_t f2b(float f){
  uint32_t x; __builtin_memcpy(&x,&f,4);
  uint32_t r = (x + 0x7FFFu + ((x>>16)&1u)) >> 16;
  return (uint16_t)r;
}

// ---------------- utility ----------------
__global__ void k_zero2(int* __restrict__ a, int* __restrict__ b, int n){
  int i = blockIdx.x*blockDim.x + threadIdx.x;
  if(i<n){ a[i]=0; b[i]=0; }
}

// ---------------- CSR build over (dst*8+etype) buckets ----------------
__global__ void k_hist(const int* __restrict__ dst, const int* __restrict__ et,
                       int* __restrict__ deg){
  int i = blockIdx.x*blockDim.x + threadIdx.x;
  if(i<N_EDGES) atomicAdd(&deg[dst[i]*NREL + et[i]],1);
}

__global__ void k_scan1(const int* __restrict__ in, int* __restrict__ out,
                        int* __restrict__ part, int n){
  __shared__ int sm[256];
  int t = threadIdx.x; int i = blockIdx.x*256+t;
  int v = (i<n)? in[i] : 0;
  sm[t]=v; __syncthreads();
  for(int off=1; off<256; off<<=1){
    int x = (t>=off)? sm[t-off] : 0;
    __syncthreads();
    sm[t]+=x;
    __syncthreads();
  }
  if(i<n) out[i]=sm[t]-v;       // exclusive within block
  if(t==255) part[blockIdx.x]=sm[255];
}

__global__ void k_scan2(int* __restrict__ part, int nb){
  __shared__ int sm[256];
  int t=threadIdx.x;
  int v=(t<nb)? part[t] : 0;
  sm[t]=v; __syncthreads();
  for(int off=1; off<256; off<<=1){
    int x=(t>=off)? sm[t-off]:0;
    __syncthreads();
    sm[t]+=x;
    __syncthreads();
  }
  if(t<nb) part[t]=sm[t]-v;
}

__global__ void k_scan3(int* __restrict__ out, const int* __restrict__ part, int n){
  int i = blockIdx.x*blockDim.x+threadIdx.x;
  if(i<n) out[i]+=part[blockIdx.x];
}

__global__ void k_scatter(const int* __restrict__ src, const int* __restrict__ et,
                          const float* __restrict__ w, const int* __restrict__ dst,
                          const int* __restrict__ offs, int* __restrict__ cur,
                          int2* __restrict__ es){
  int i = blockIdx.x*blockDim.x + threadIdx.x;
  if(i<N_EDGES){
    int b = dst[i]*NREL + et[i];
    int pos = offs[b] + atomicAdd(&cur[b],1);
    int2 e; e.x = src[i]; e.y = __float_as_int(w[i]);
    es[pos] = e;
  }
}

// ---------------- f32 -> bf16 table convert ----------------
__global__ void k_f2b(const float* __restrict__ in, ushortT* __restrict__ out, int n4){
  int i = blockIdx.x*blockDim.x + threadIdx.x;
  if(i<n4){
    float4 v = ((const float4*)in)[i];
    ushort4 o;
    o.x=f2b(v.x); o.y=f2b(v.y); o.z=f2b(v.z); o.w=f2b(v.w);
    ((ushort4*)out)[i]=o;
  }
}

// ---------------- Wt[o][r*128+k] = sum_b comp[r,b] V[b,k,o] (both layers) ----
__global__ void k_relw(const float* __restrict__ comp1, const float* __restrict__ V1,
                       const float* __restrict__ comp2, const float* __restrict__ V2,
                       ushortT* __restrict__ Wt1, ushortT* __restrict__ Wt2){
  int t = blockIdx.x*blockDim.x + threadIdx.x;
  int layer = t >> 17;             // 0 or 1 (2*131072 threads)
  t &= 131071;
  const float* comp = layer? comp2 : comp1;
  const float* V    = layer? V2    : V1;
  ushortT* Wt       = layer? Wt2   : Wt1;
  int o  = t >> 10;                // 0..127
  int rk = t & 1023;
  int r  = rk >> 7, k = rk & 127;
  float s=0.f;
  #pragma unroll
  for(int b=0;b<NREL;b++) s += comp[r*NREL+b]*V[(b<<14) + k*HD + o];
  Wt[t]=f2b(s);
}

// ---------------- aggregate-first: 4 buckets per WAVE ----------------
// lane = q*16+f : quarter q owns bucket wave*4+q, lane covers bytes [f*16, f*16+16)
// Acat[b][128] bf16, b = node*8+r  (== A[node][1024] r-major)
__global__ void __launch_bounds__(256)
k_agg(const ushortT* __restrict__ xb,   // [N][128] bf16 gather table
      const int* __restrict__ offs, const int* __restrict__ deg,
      const int2* __restrict__ es,      // packed (src, w)
      ushortT* __restrict__ Acat){
  int wave = blockIdx.x*4 + (threadIdx.x>>6);
  int lane = threadIdx.x & 63;
  int q = lane >> 4, f = lane & 15;
  int b = wave*4 + q;                   // NBUCK divisible by 4; grid sized exactly
  int beg = offs[b], cnt = deg[b];
  const int2* ep = es + beg;
  float a[8] = {};
  int2 e; e.x = 0; e.y = 0;
  if(cnt > 0) e = ep[0];                // masked prefetch (no OOB when cnt==0)
  for(int j=0;j<cnt;j++){
    int2 ce = e;
    if(j+1 < cnt) e = ep[j+1];          // prefetch next edge while gathering
    float w = __int_as_float(ce.y);
    bf16x8 v = *(const bf16x8*)&xb[(size_t)ce.x*HD + f*8];
    #pragma unroll
    for(int t=0;t<8;t++) a[t] += w * b2f((uint16_t)v[t]);
  }
  uint32_t pk[4];
  #pragma unroll
  for(int i=0;i<4;i++)
    pk[i] = (uint32_t)f2b(a[2*i]) | ((uint32_t)f2b(a[2*i+1])<<16);
  // wave writes 4 adjacent 256B rows -> 1KB contiguous
  *(uint4*)&Acat[(size_t)b*HD + f*8] = *(uint4*)pk;
}

// ---------------- MFMA GEMM: out[M][128] = Acat[M][1024] @ Wt^T ----------------
constexpr int BM=64, BN=128, BK=64, LDK=72;   // pad: 144B row, 2-way bank alias (free)
__global__ void __launch_bounds__(256)
k_gemm(const ushortT* __restrict__ A,   // [M][1024] bf16
       const ushortT* __restrict__ Wt,  // [128][1024] bf16 (B transposed)
       const float* __restrict__ bias,
       float* __restrict__ outF,        // layer2 output (f32) or null
       ushortT* __restrict__ outB,      // layer1 output (bf16) or null
       int M, int relu){
  __shared__ ushortT Asm[BM][LDK];
  __shared__ ushortT Bsm[BN][LDK];
  int tid = threadIdx.x;
  int wid = tid>>6, lane = tid&63;
  int l15 = lane&15, lhi = lane>>4;
  int row0 = blockIdx.x*BM;
  int wr = (wid>>1)*32, wc = (wid&1)*64;   // wave tile 32x64
  f32x4 acc[2][4] = {};
  for(int kt=0; kt<NREL*HD; kt+=BK){
    #pragma unroll
    for(int q=0;q<2;q++){
      int slot = q*256 + tid;
      int r = slot>>3, kb8 = (slot&7)*8;
      int grow = row0 + r; if(grow >= M) grow = M-1;
      *(bf16x8*)&Asm[r][kb8] = *(const bf16x8*)&A[(size_t)grow*1024 + kt + kb8];
    }
    #pragma unroll
    for(int q=0;q<4;q++){
      int slot = q*256 + tid;
      int c = slot>>3, kb8 = (slot&7)*8;
      *(bf16x8*)&Bsm[c][kb8] = *(const bf16x8*)&Wt[(size_t)c*1024 + kt + kb8];
    }
    __syncthreads();
    #pragma unroll
    for(int kk=0;kk<2;kk++){
      bf16x8 af[2], bfr[4];
      #pragma unroll
      for(int m=0;m<2;m++)  af[m]  = *(const bf16x8*)&Asm[wr + m*16 + l15][kk*32 + lhi*8];
      #pragma unroll
      for(int n=0;n<4;n++)  bfr[n] = *(const bf16x8*)&Bsm[wc + n*16 + l15][kk*32 + lhi*8];
      #pragma unroll
      for(int m=0;m<2;m++)
        #pragma unroll
        for(int n=0;n<4;n++)
          acc[m][n] = __builtin_amdgcn_mfma_f32_16x16x32_bf16(af[m], bfr[n], acc[m][n], 0,0,0);
    }
    __syncthreads();
  }
  #pragma unroll
  for(int m=0;m<2;m++){
    #pragma unroll
    for(int j=0;j<4;j++){
      int grow = row0 + wr + m*16 + lhi*4 + j;
      if(grow < M){
        #pragma unroll
        for(int n=0;n<4;n++){
          int col = wc + n*16 + l15;
          float v = acc[m][n][j] + bias[col];
          if(relu) v = fmaxf(v, 0.f);
          if(outF) outF[(size_t)grow*HD + col] = v;
          else     outB[(size_t)grow*HD + col] = f2b(v);
        }
      }
    }
  }
}

extern "C" void kernel_launch(void* const* d_in, const int* in_sizes, int n_in,
                              void* d_out, int out_size, void* d_ws, size_t ws_size,
                              hipStream_t stream){
  const float* feat  = (const float*)d_in[0];
  const int*   etyp  = (const int*)  d_in[1];
  const float* ew    = (const float*)d_in[2];
  const int*   src   = (const int*)  d_in[3];
  const int*   dst   = (const int*)  d_in[4];
  const float* comp1 = (const float*)d_in[5];
  const float* V1    = (const float*)d_in[6];
  const float* bias1 = (const float*)d_in[7];
  const float* comp2 = (const float*)d_in[8];
  const float* V2    = (const float*)d_in[9];
  const float* bias2 = (const float*)d_in[10];
  float* out = (float*)d_out;

  char* p = (char*)d_ws;
  auto alloc = [&](size_t bytes)->char* {
    char* q = p; p += (bytes + 255) & ~(size_t)255; return q;
  };
  ushortT* Wt1   = (ushortT*)alloc((size_t)HD*NREL*HD*2);        // 256 KB
  ushortT* Wt2   = (ushortT*)alloc((size_t)HD*NREL*HD*2);        // 256 KB
  ushortT* Acat  = (ushortT*)alloc((size_t)N_NODES*NREL*HD*2);   // 102.4 MB
  ushortT* xb    = (ushortT*)alloc((size_t)N_NODES*HD*2);        // 12.8 MB
  ushortT* hmid  = (ushortT*)alloc((size_t)N_NODES*HD*2);        // 12.8 MB
  int*   deg   = (int*)  alloc((size_t)NBUCK*4);
  int*   offs  = (int*)  alloc((size_t)NBUCK*4);
  int*   cur   = (int*)  alloc((size_t)NBUCK*4);
  int*   part1 = (int*)  alloc(2048*4);
  int*   part2 = (int*)  alloc(256*4);
  int2*  es    = (int2*) alloc((size_t)N_EDGES*8);

  // ---- CSR build over 400k (dst,etype) buckets ----
  int zb = (NBUCK+255)/256;           // 1563
  k_zero2<<<zb,256,0,stream>>>(deg,cur,NBUCK);
  k_hist<<<(N_EDGES+255)/256,256,0,stream>>>(dst,etyp,deg);
  int nb1 = (NBUCK+255)/256;          // 1563
  int nb2 = (nb1+255)/256;            // 7
  k_scan1<<<nb1,256,0,stream>>>(deg,offs,part1,NBUCK);
  k_scan1<<<nb2,256,0,stream>>>(part1,part1,part2,nb1);
  k_scan2<<<1,256,0,stream>>>(part2,nb2);
  k_scan3<<<nb2,256,0,stream>>>(part1,part2,nb1);
  k_scan3<<<nb1,256,0,stream>>>(offs,part1,NBUCK);
  k_scatter<<<(N_EDGES+255)/256,256,0,stream>>>(src,etyp,ew,dst,offs,cur,es);

  // ---- feature table to bf16; relation weights for both layers ----
  int n4 = N_NODES*HD/4;
  k_f2b<<<(n4+255)/256,256,0,stream>>>(feat, xb, n4);
  k_relw<<<(2*HD*NREL*HD+255)/256,256,0,stream>>>(comp1,V1,comp2,V2,Wt1,Wt2);

  int aggGrid  = NBUCK/16;                // 25000 blocks: 4 waves x 4 buckets each
  int gemmGrid = (N_NODES + BM - 1)/BM;   // 782
  // ---- layer 1 ----
  k_agg<<<aggGrid,256,0,stream>>>(xb,   offs, deg, es, Acat);
  k_gemm<<<gemmGrid,256,0,stream>>>(Acat, Wt1, bias1, nullptr, hmid, N_NODES, 1);
  // ---- layer 2 ----
  k_agg<<<aggGrid,256,0,stream>>>(hmid, offs, deg, es, Acat);
  k_gemm<<<gemmGrid,256,0,stream>>>(Acat, Wt2, bias2, out, nullptr, N_NODES, 0);
}